// Round 1
// baseline (148.814 us; speedup 1.0000x reference)
//
#include <hip/hip_runtime.h>

// Fused ConvNet: conv7x7 s3 (3->4) -> ^2 -> FC 324->64 -> ^2 -> FC 64->10
// B = 16384, fp32 throughout.

#define CIN    3
#define COUT   4
#define KK     7
#define STR    3
#define HIN    32
#define HOUTN  9
#define NPOS   81      // 9*9
#define FC1_IN 324     // 4*81
#define HID    64
#define NOUT   10
#define RS     36              // padded LDS row stride (floats); 32 data + 4 pad
#define CS     (RS * HIN)      // 1152 floats per channel plane
#define XS_F   (CIN * CS)      // 3456 floats per sample

__global__ __launch_bounds__(128) void convnet_fused(
    const float* __restrict__ x,
    const float* __restrict__ cw,     // [4][3][7][7]
    const float* __restrict__ fc1w,   // [64][324]
    const float* __restrict__ fc1b,   // [64]
    const float* __restrict__ fc2w,   // [10][64]
    const float* __restrict__ fc2b,   // [10]
    float* __restrict__ out)          // [B][10]
{
    __shared__ float xs[2][XS_F];      // 27648 B
    __shared__ float ysq[2][FC1_IN];   //  2592 B
    __shared__ float hsq[2][HID];      //   512 B

    const int t    = threadIdx.x;
    const int lane = t & 63;
    const int w    = t >> 6;               // wave id == local sample id
    const int bs   = blockIdx.x * 2;       // first sample of this block

    // ---------------- stage x (coalesced float4 -> padded LDS) ----------------
    const float4* xg = reinterpret_cast<const float4*>(x) + (size_t)(bs + w) * 768;
    #pragma unroll
    for (int i = 0; i < 12; ++i) {
        int r4 = i * 64 + lane;            // float4 index within sample
        float4 v = xg[r4];
        int flat = r4 * 4;                 // float index
        int c    = flat >> 10;             // /1024
        int rem  = flat & 1023;
        int row  = rem >> 5;               // /32
        int col  = rem & 31;
        *reinterpret_cast<float4*>(&xs[w][c * CS + row * RS + col]) = v;
    }
    __syncthreads();

    // ---------------- conv 7x7 stride 3 + square ----------------
    // lane -> output position p (81 positions, 2 reps); 4 oc accumulators.
    // conv weights: indices are loop constants -> uniform -> scalar loads.
    #pragma unroll
    for (int rep = 0; rep < 2; ++rep) {
        int p = lane + rep * 64;
        if (p < NPOS) {
            int oh = p / 9;
            int ow = p - oh * 9;
            const float* xb = &xs[w][oh * (STR * RS) + ow * STR];
            float a0 = 0.f, a1 = 0.f, a2 = 0.f, a3 = 0.f;
            #pragma unroll
            for (int ci = 0; ci < CIN; ++ci) {
                #pragma unroll
                for (int kh = 0; kh < KK; ++kh) {
                    const float* xr = xb + ci * CS + kh * RS;
                    #pragma unroll
                    for (int kw = 0; kw < KK; ++kw) {
                        float xv = xr[kw];
                        int wi = ci * 49 + kh * 7 + kw;
                        a0 += xv * cw[          wi];
                        a1 += xv * cw[147     + wi];
                        a2 += xv * cw[294     + wi];
                        a3 += xv * cw[441     + wi];
                    }
                }
            }
            ysq[w][0 * NPOS + p] = a0 * a0;
            ysq[w][1 * NPOS + p] = a1 * a1;
            ysq[w][2 * NPOS + p] = a2 * a2;
            ysq[w][3 * NPOS + p] = a3 * a3;
        }
    }
    __syncthreads();   // cheap safety barrier (also orders ysq for fc1)

    // ---------------- fc1 (324 -> 64) + square ----------------
    // lane = hidden unit; ysq reads are wave-uniform (LDS broadcast).
    {
        const float* wr = fc1w + lane * FC1_IN;   // 1296 B row, 16B aligned
        const float* yv = ysq[w];
        float acc0 = fc1b[lane];
        float acc1 = 0.f;
        #pragma unroll 1
        for (int k = 0; k < 320; k += 8) {
            float4 w0 = *reinterpret_cast<const float4*>(wr + k);
            float4 w1 = *reinterpret_cast<const float4*>(wr + k + 4);
            acc0 += w0.x * yv[k]     + w0.y * yv[k + 1] + w0.z * yv[k + 2] + w0.w * yv[k + 3];
            acc1 += w1.x * yv[k + 4] + w1.y * yv[k + 5] + w1.z * yv[k + 6] + w1.w * yv[k + 7];
        }
        {   // tail k = 320..323
            float4 w0 = *reinterpret_cast<const float4*>(wr + 320);
            acc0 += w0.x * yv[320] + w0.y * yv[321] + w0.z * yv[322] + w0.w * yv[323];
        }
        float h = acc0 + acc1;
        hsq[w][lane] = h * h;
    }
    __syncthreads();

    // ---------------- fc2 (64 -> 10) ----------------
    if (t < 2 * NOUT) {
        int sl = t / NOUT;
        int j  = t - sl * NOUT;
        float acc = fc2b[j];
        const float* wr = fc2w + j * HID;
        const float* hv = hsq[sl];
        #pragma unroll
        for (int i = 0; i < HID; ++i) acc += wr[i] * hv[i];
        out[(size_t)(bs + sl) * NOUT + j] = acc;
    }
}

extern "C" void kernel_launch(void* const* d_in, const int* in_sizes, int n_in,
                              void* d_out, int out_size, void* d_ws, size_t ws_size,
                              hipStream_t stream) {
    const float* x    = (const float*)d_in[0];
    const float* cw   = (const float*)d_in[1];
    const float* fc1w = (const float*)d_in[2];
    const float* fc1b = (const float*)d_in[3];
    const float* fc2w = (const float*)d_in[4];
    const float* fc2b = (const float*)d_in[5];
    float* out = (float*)d_out;

    const int B = in_sizes[0] / (CIN * HIN * HIN);   // 16384
    dim3 grid(B / 2), block(128);
    hipLaunchKernelGGL(convnet_fused, grid, block, 0, stream,
                       x, cw, fc1w, fc1b, fc2w, fc2b, out);
}

// Round 2
// 125.521 us; speedup vs baseline: 1.1856x; 1.1856x over previous
//
#include <hip/hip_runtime.h>
#include <string.h>

// Fused ConvNet: conv7x7 s3 (3->4) -> ^2 -> FC 324->64 -> ^2 -> FC 64->10
// B = 16384. x staged in LDS as fp16 (RTZ); all accumulation fp32.
//
// Block = 256 threads (4 waves) processes 16 samples.
// LDS map (bytes):
//   union [0, 16448):
//     phase-A: XS fp16 [3][32][36] @0 (6912) ; PART f32 [4][81][4] @6912 (5184)
//     phase-B: RED f32 [3][16][64] @0 (12288); HSQ f32 [16][65] @12288 (4160)
//   YSQ f32 [16][81][4] @16448 (20736)   -> total 37184 -> 4 blocks/CU

typedef __fp16 half2v __attribute__((ext_vector_type(2)));

#define LDS_BYTES 37184
#define PART_OFF  6912
#define HSQ_OFF   12288
#define YSQ_OFF   16448

__device__ __forceinline__ unsigned pack_rtz(float a, float b) {
    half2v h = __builtin_amdgcn_cvt_pkrtz(a, b);
    unsigned u; memcpy(&u, &h, 4);
    return u;
}
__device__ __forceinline__ float2 up2(unsigned u) {
    half2v h; memcpy(&h, &u, 4);
    return make_float2((float)h.x, (float)h.y);
}

// ---- conv for windows [LO, HI), window widx = ci*7+kh ----
template<int LO, int HI>
__device__ __forceinline__ void conv_taps(const unsigned long long* __restrict__ XQ,
                                          const float* __restrict__ cw,
                                          int baseq, bool hi2, int resid,
                                          float& a0, float& a1, float& a2, float& a3) {
#pragma unroll
    for (int widx = LO; widx < HI; ++widx) {
        const int ci = widx / 7, kh = widx % 7;
        const int qo = baseq + ci * 288 + kh * 9;
        unsigned long long q0 = XQ[qo], q1 = XQ[qo + 1], q2 = XQ[qo + 2];
        unsigned r0 = (unsigned)q0, r1 = (unsigned)(q0 >> 32);
        unsigned r2 = (unsigned)q1, r3 = (unsigned)(q1 >> 32);
        unsigned r4 = (unsigned)q2, r5 = (unsigned)(q2 >> 32);
        // skip one dword if sh_halves >= 2
        unsigned b0 = hi2 ? r1 : r0;
        unsigned b1 = hi2 ? r2 : r1;
        unsigned b2 = hi2 ? r3 : r2;
        unsigned b3 = hi2 ? r4 : r3;
        unsigned b4 = hi2 ? r5 : r4;
        unsigned o0 = __builtin_amdgcn_alignbit(b1, b0, resid);
        unsigned o1 = __builtin_amdgcn_alignbit(b2, b1, resid);
        unsigned o2 = __builtin_amdgcn_alignbit(b3, b2, resid);
        unsigned o3 = __builtin_amdgcn_alignbit(b4, b3, resid);
        float2 f01 = up2(o0), f23 = up2(o1), f45 = up2(o2), f6x = up2(o3);
        const float* wb = cw + widx * 7;   // cw[oc*147 + widx*7 + kw]
#pragma unroll
        for (int oc = 0; oc < 4; ++oc) {
            const float* wr = wb + oc * 147;
            float s = f01.x * wr[0] + f01.y * wr[1] + f23.x * wr[2] + f23.y * wr[3]
                    + f45.x * wr[4] + f45.y * wr[5] + f6x.x * wr[6];
            if (oc == 0) a0 += s; else if (oc == 1) a1 += s; else if (oc == 2) a2 += s; else a3 += s;
        }
    }
}

__global__ void transpose_fc1w(const float* __restrict__ fc1w, float* __restrict__ wt) {
    int idx = blockIdx.x * 256 + threadIdx.x;   // 0..20735
    int k = idx >> 6, h = idx & 63;
    wt[idx] = fc1w[h * 324 + k];                // wt[k][h]
}

__global__ __launch_bounds__(256, 4) void convnet_main(
    const float* __restrict__ x,
    const float* __restrict__ cw,      // [4][3][7][7]
    const float* __restrict__ wt,      // [324][64] transposed fc1w (in ws)
    const float* __restrict__ fc1b,
    const float* __restrict__ fc2w,    // [10][64]
    const float* __restrict__ fc2b,
    float* __restrict__ out)
{
    __shared__ unsigned char lds[LDS_BYTES];
    __fp16*  XS   = (__fp16*)lds;                                 // [3][32][36] halves
    const unsigned long long* XQ = (const unsigned long long*)lds; // qword view
    float* PART = (float*)(lds + PART_OFF);                        // [4][81][4]
    float* RED  = (float*)lds;                                     // [3][16][64]
    float* HSQ  = (float*)(lds + HSQ_OFF);                         // [16][65]
    float* YSQ  = (float*)(lds + YSQ_OFF);                         // [16][81][4]

    const int t    = threadIdx.x;
    const int lane = t & 63;
    const int w    = t >> 6;
    const size_t base_s = (size_t)blockIdx.x * 16;

    // per-lane conv geometry (rep 0: p = lane; rep 1: p = 64+lane)
    // computed inside the loop below.

    // ---------- prologue: stage sample 0 ----------
    {
        const float4* xg = (const float4*)(x + base_s * 3072);
#pragma unroll
        for (int r = 0; r < 3; ++r) {
            int idx = r * 256 + t;               // 0..767
            int ci = idx >> 8, rem = idx & 255;
            int row = rem >> 3, q = rem & 7;
            float4 v = xg[idx];
            unsigned u0 = pack_rtz(v.x, v.y), u1 = pack_rtz(v.z, v.w);
            unsigned long long uu = ((unsigned long long)u1 << 32) | u0;
            *(unsigned long long*)(&XS[ci * 1152 + row * 36 + q * 4]) = uu;
        }
    }
    __syncthreads();

    // ---------- 16 samples: conv -> partials -> (stage next | combine) ----------
    for (int s = 0; s < 16; ++s) {
        // conv: each wave covers its tap windows for all 81 positions (2 reps)
#pragma unroll
        for (int rep = 0; rep < 2; ++rep) {
            int p = rep * 64 + lane;
            bool act = p < 81;
            int pc = act ? p : 0;
            int oh = (pc * 57) >> 9;
            int ow = pc - oh * 9;
            int baseq = 27 * oh + ((3 * ow) >> 2);
            int shh = (3 * ow) & 3;              // halves to skip
            bool hi2 = shh >= 2;
            int resid = (shh & 1) ? 16 : 0;
            float a0 = 0.f, a1 = 0.f, a2 = 0.f, a3 = 0.f;
            if (w == 0)      conv_taps<0, 6 >(XQ, cw, baseq, hi2, resid, a0, a1, a2, a3);
            else if (w == 1) conv_taps<6, 11>(XQ, cw, baseq, hi2, resid, a0, a1, a2, a3);
            else if (w == 2) conv_taps<11,16>(XQ, cw, baseq, hi2, resid, a0, a1, a2, a3);
            else             conv_taps<16,21>(XQ, cw, baseq, hi2, resid, a0, a1, a2, a3);
            if (act) {
                float4 v = make_float4(a0, a1, a2, a3);
                *(float4*)&PART[w * 324 + p * 4] = v;
            }
        }
        __syncthreads();

        // stage next sample (xs free: conv done) + combine partials -> ysq[s]
        if (s < 15) {
            const float4* xg = (const float4*)(x + (base_s + s + 1) * 3072);
#pragma unroll
            for (int r = 0; r < 3; ++r) {
                int idx = r * 256 + t;
                int ci = idx >> 8, rem = idx & 255;
                int row = rem >> 3, q = rem & 7;
                float4 v = xg[idx];
                unsigned u0 = pack_rtz(v.x, v.y), u1 = pack_rtz(v.z, v.w);
                unsigned long long uu = ((unsigned long long)u1 << 32) | u0;
                *(unsigned long long*)(&XS[ci * 1152 + row * 36 + q * 4]) = uu;
            }
        }
        if (t < 81) {
            float4 s0 = *(float4*)&PART[        t * 4];
            float4 s1 = *(float4*)&PART[324  +  t * 4];
            float4 s2 = *(float4*)&PART[648  +  t * 4];
            float4 s3 = *(float4*)&PART[972  +  t * 4];
            float y0 = s0.x + s1.x + s2.x + s3.x;
            float y1 = s0.y + s1.y + s2.y + s3.y;
            float y2 = s0.z + s1.z + s2.z + s3.z;
            float y3 = s0.w + s1.w + s2.w + s3.w;
            float4 yq = make_float4(y0 * y0, y1 * y1, y2 * y2, y3 * y3);
            *(float4*)&YSQ[(s * 81 + t) * 4] = yq;
        }
        __syncthreads();
    }

    // ---------- fc1: waves split k-range (p in [plo,phi), all 4 oc) ----------
    float acc[16];
#pragma unroll
    for (int s = 0; s < 16; ++s) acc[s] = 0.f;
    {
        const int plo = 20 * w;
        const int phi = (w == 3) ? 81 : plo + 20;
        for (int p = plo; p < phi; ++p) {
            float w0 = wt[(      p) * 64 + lane];
            float w1 = wt[( 81 + p) * 64 + lane];
            float w2 = wt[(162 + p) * 64 + lane];
            float w3 = wt[(243 + p) * 64 + lane];
#pragma unroll
            for (int s = 0; s < 16; ++s) {
                float4 y = *(const float4*)&YSQ[(s * 81 + p) * 4];
                acc[s] += w0 * y.x + w1 * y.y + w2 * y.z + w3 * y.w;
            }
        }
    }
    if (w >= 1) {
#pragma unroll
        for (int s = 0; s < 16; ++s) RED[(w - 1) * 1024 + s * 64 + lane] = acc[s];
    }
    __syncthreads();
    if (w == 0) {
        float b = fc1b[lane];
#pragma unroll
        for (int s = 0; s < 16; ++s) {
            float tot = acc[s] + RED[s * 64 + lane] + RED[1024 + s * 64 + lane]
                      + RED[2048 + s * 64 + lane] + b;
            HSQ[s * 65 + lane] = tot * tot;
        }
    }
    __syncthreads();

    // ---------- fc2: 160 outputs ----------
    if (t < 160) {
        int sj = t / 10, j = t - sj * 10;
        float a = fc2b[j];
        const float* wr = fc2w + j * 64;
        const float* hv = &HSQ[sj * 65];
#pragma unroll
        for (int i = 0; i < 64; ++i) a += wr[i] * hv[i];
        out[(base_s + sj) * 10 + j] = a;
    }
}

extern "C" void kernel_launch(void* const* d_in, const int* in_sizes, int n_in,
                              void* d_out, int out_size, void* d_ws, size_t ws_size,
                              hipStream_t stream) {
    const float* x    = (const float*)d_in[0];
    const float* cw   = (const float*)d_in[1];
    const float* fc1w = (const float*)d_in[2];
    const float* fc1b = (const float*)d_in[3];
    const float* fc2w = (const float*)d_in[4];
    const float* fc2b = (const float*)d_in[5];
    float* out = (float*)d_out;
    float* wt  = (float*)d_ws;                 // 324*64*4 = 82944 bytes

    hipLaunchKernelGGL(transpose_fc1w, dim3(81), dim3(256), 0, stream, fc1w, wt);

    const int B = in_sizes[0] / 3072;          // 16384
    hipLaunchKernelGGL(convnet_main, dim3(B / 16), dim3(256), 0, stream,
                       x, cw, wt, fc1b, fc2w, fc2b, out);
}

// Round 4
// 53.309 us; speedup vs baseline: 2.7915x; 2.3546x over previous
//
#include <hip/hip_runtime.h>
#include <string.h>

// Fused ConvNet on MFMA: conv7x7 s3 (3->4) -> ^2 -> FC 324->64 -> ^2 -> FC 64->10
// conv + fc1 run on v_mfma_f32_16x16x32_f16 with fp16 hi/lo weight splitting.
// Block = 256 thr (4 waves) = 16 samples; pairs of samples double-buffered in LDS.

typedef _Float16 f16;
typedef f16 f16x8 __attribute__((ext_vector_type(8)));
typedef __fp16 fp16x2 __attribute__((ext_vector_type(2)));
typedef float f32x4 __attribute__((ext_vector_type(4)));
typedef unsigned long long ull;

#define YSQ_B   27648                  // byte offset of YSQ region
#define LDS_B   (27648 + 11520)       // XS[2][2][3456]h + YSQ[16][360]h

__device__ __forceinline__ unsigned pack_rtz(float a, float b) {
    fp16x2 h = __builtin_amdgcn_cvt_pkrtz(a, b);
    unsigned u; memcpy(&u, &h, 4); return u;
}

__device__ __forceinline__ void stage_pair(f16* XSH, int buf, const float4 ld[6], int t) {
#pragma unroll
    for (int i = 0; i < 6; ++i) {
        int idx = i * 256 + t;                 // 0..1535 (2 samples x 768 float4)
        int sp  = idx >= 768;
        int within = idx - sp * 768;
        int ci  = within >> 8;
        int rem = within & 255;
        int row = rem >> 3;
        int q   = rem & 7;
        int h0  = buf * 6912 + sp * 3456 + ci * 1152 + row * 36 + q * 4;
        float4 v = ld[i];
        unsigned u0 = pack_rtz(v.x, v.y), u1 = pack_rtz(v.z, v.w);
        *(ull*)(XSH + h0) = ((ull)u1 << 32) | u0;
    }
}

// ---------------- weight prep: fp16 hi/lo transposed layouts in ws ----------------
// w1t: [2][64][352] f16  (fc1, k = oc*81+p, zero-padded k>=324)
// wct: [2][16][192] f16  (conv, row = oc (>=4 zero), k = seg*8 + kw, seg=(ci*7+kh), kw<7 real)
__global__ void prep_weights(const float* __restrict__ cw, const float* __restrict__ fc1w,
                             f16* __restrict__ w1t, f16* __restrict__ wct) {
    int idx = blockIdx.x * 256 + threadIdx.x;
    if (idx < 45056) {
        int part = idx / 22528;
        int rem  = idx % 22528;
        int n = rem / 352, k = rem % 352;
        float v = (k < 324) ? fc1w[n * 324 + k] : 0.f;
        f16 hi = (f16)v;
        w1t[idx] = (part == 0) ? hi : (f16)(v - (float)hi);
    } else if (idx < 45056 + 6144) {
        int j = idx - 45056;
        int part = j / 3072;
        int rem  = j % 3072;
        int oc = rem / 192, k = rem % 192;
        int seg = k >> 3, kw = k & 7;
        float v = 0.f;
        if (oc < 4 && seg < 21 && kw < 7) {
            int ci = seg / 7, kh = seg % 7;
            v = cw[((oc * 3 + ci) * 7 + kh) * 7 + kw];
        }
        f16 hi = (f16)v;
        wct[j] = (part == 0) ? hi : (f16)(v - (float)hi);
    }
}

__global__ __launch_bounds__(256, 4) void convnet_mfma(
    const float* __restrict__ x,
    const f16*  __restrict__ w1t,     // [2][64][352]
    const f16*  __restrict__ wct,     // [2][16][192]
    const float* __restrict__ fc1b,
    const float* __restrict__ fc2w,
    const float* __restrict__ fc2b,
    float* __restrict__ out)
{
    __shared__ unsigned char lds[LDS_B];
    f16* XSH = (f16*)lds;                                   // [2][2][3456] halves
    const ull* XQ = (const ull*)lds;                        // qword view of XS
    f16* YS = (f16*)(lds + YSQ_B);                          // [16][360] halves
    float* HSQ = (float*)lds;                               // overlay on XS (post-conv)

    const int t    = threadIdx.x;
    const int lane = t & 63;
    const int w    = t >> 6;
    const int g    = lane >> 4;        // lane group (k-group / row-quad)
    const int lr   = lane & 15;        // A-row-in-tile / B-col
    const size_t base_s = (size_t)blockIdx.x * 16;

    // hoist conv W fragments: [part][step], lane holds col=lr, k=step*32+g*8 ..+7
    f16x8 wc[2][6];
#pragma unroll
    for (int part = 0; part < 2; ++part)
#pragma unroll
        for (int st = 0; st < 6; ++st)
            wc[part][st] = *(const f16x8*)(wct + part * 3072 + lr * 192 + st * 32 + g * 8);

    // issue pair-0 loads
    float4 ld[6];
    {
        const float4* xg = (const float4*)(x + base_s * 3072);
#pragma unroll
        for (int i = 0; i < 6; ++i) ld[i] = xg[i * 256 + t];
    }
    // zero YSQ (kills stale NaNs in pad region)
#pragma unroll
    for (int i = 0; i < 3; ++i) {
        int idx = i * 256 + t;
        if (idx < 720) *(f32x4*)(lds + YSQ_B + idx * 16) = f32x4{0.f, 0.f, 0.f, 0.f};
    }
    stage_pair(XSH, 0, ld, t);
    __syncthreads();

    int buf = 0;
    for (int pair = 0; pair < 8; ++pair) {
        if (pair < 7) {
            const float4* xg = (const float4*)(x + (base_s + (size_t)(pair + 1) * 2) * 3072);
#pragma unroll
            for (int i = 0; i < 6; ++i) ld[i] = xg[i * 256 + t];
        }
        // conv tiles of this pair: 162 rows -> 11 tiles of 16, round-robin over waves
        for (int tile = (w + pair) & 3; tile < 11; tile += 4) {
            int grow  = tile * 16 + lr;
            int growc = grow > 161 ? 161 : grow;
            int sp  = growc >= 81;
            int p   = growc - (sp ? 81 : 0);
            int oh  = (p * 57) >> 9;
            int ow  = p - oh * 9;
            int c3  = 3 * ow;
            int resid = c3 & 3;
            bool hi2  = resid >= 2;
            int sh    = (resid & 1) << 4;
            int qbase = buf * 1728 + sp * 864 + (c3 >> 2);
            f32x4 acc = {0.f, 0.f, 0.f, 0.f};
#pragma unroll
            for (int st = 0; st < 6; ++st) {
                int seg  = st * 4 + g;
                int segc = seg > 20 ? 20 : seg;           // pad segs read valid addr; W=0 kills them
                int ci   = segc >= 14 ? 2 : (segc >= 7 ? 1 : 0);
                int kh   = segc - ci * 7;
                int qo   = qbase + ci * 288 + (3 * oh + kh) * 9;
                ull q0 = XQ[qo], q1 = XQ[qo + 1], q2 = XQ[qo + 2];
                unsigned r0 = (unsigned)q0, r1 = (unsigned)(q0 >> 32);
                unsigned r2 = (unsigned)q1, r3 = (unsigned)(q1 >> 32);
                unsigned r4 = (unsigned)q2, r5 = (unsigned)(q2 >> 32);
                unsigned b0 = hi2 ? r1 : r0, b1 = hi2 ? r2 : r1, b2 = hi2 ? r3 : r2;
                unsigned b3 = hi2 ? r4 : r3, b4 = hi2 ? r5 : r4;
                union { unsigned u[4]; f16x8 h; } af;
                af.u[0] = __builtin_amdgcn_alignbit(b1, b0, sh);
                af.u[1] = __builtin_amdgcn_alignbit(b2, b1, sh);
                af.u[2] = __builtin_amdgcn_alignbit(b3, b2, sh);
                af.u[3] = __builtin_amdgcn_alignbit(b4, b3, sh);
                acc = __builtin_amdgcn_mfma_f32_16x16x32_f16(af.h, wc[0][st], acc, 0, 0, 0);
                acc = __builtin_amdgcn_mfma_f32_16x16x32_f16(af.h, wc[1][st], acc, 0, 0, 0);
            }
            // C: col=lr(oc), row=g*4+r -> y^2 as fp16 into YS[sample][oc*81+p]
            if (lr < 4) {
#pragma unroll
                for (int r = 0; r < 4; ++r) {
                    int gr = tile * 16 + g * 4 + r;
                    if (gr < 162) {
                        int sp2 = gr >= 81;
                        int p2  = gr - (sp2 ? 81 : 0);
                        float y = acc[r];
                        YS[(pair * 2 + sp2) * 360 + lr * 81 + p2] = (f16)(y * y);
                    }
                }
            }
        }
        if (pair < 7) stage_pair(XSH, buf ^ 1, ld, t);
        __syncthreads();
        buf ^= 1;
    }

    // ---------------- fc1: M=16 samples, N=64 (wave w -> ntile w), K=352 ----------------
    {
        f32x4 a1 = {0.f, 0.f, 0.f, 0.f};
        const int n = w * 16 + lr;
#pragma unroll
        for (int st = 0; st < 11; ++st) {
            f16x8 av = *(const f16x8*)(YS + lr * 360 + st * 32 + g * 8);
            f16x8 bh = *(const f16x8*)(w1t +          n * 352 + st * 32 + g * 8);
            f16x8 bl = *(const f16x8*)(w1t + 22528 +  n * 352 + st * 32 + g * 8);
            a1 = __builtin_amdgcn_mfma_f32_16x16x32_f16(av, bh, a1, 0, 0, 0);
            a1 = __builtin_amdgcn_mfma_f32_16x16x32_f16(av, bl, a1, 0, 0, 0);
        }
        float bias = fc1b[n];
#pragma unroll
        for (int r = 0; r < 4; ++r) {
            int s = g * 4 + r;                 // sample row
            float h = a1[r] + bias;
            HSQ[s * 65 + n] = h * h;
        }
    }
    __syncthreads();

    // ---------------- fc2: 160 outputs ----------------
    if (t < 160) {
        int sj = t / 10, j = t - sj * 10;
        float a = fc2b[j];
        const float* wr = fc2w + j * 64;
        const float* hv = &HSQ[sj * 65];
#pragma unroll
        for (int i = 0; i < 64; ++i) a += wr[i] * hv[i];
        out[(base_s + sj) * 10 + j] = a;
    }
}

extern "C" void kernel_launch(void* const* d_in, const int* in_sizes, int n_in,
                              void* d_out, int out_size, void* d_ws, size_t ws_size,
                              hipStream_t stream) {
    const float* x    = (const float*)d_in[0];
    const float* cw   = (const float*)d_in[1];
    const float* fc1w = (const float*)d_in[2];
    const float* fc1b = (const float*)d_in[3];
    const float* fc2w = (const float*)d_in[4];
    const float* fc2b = (const float*)d_in[5];
    float* out = (float*)d_out;

    f16* w1t = (f16*)d_ws;                 // 45056 f16 = 90112 B
    f16* wct = w1t + 45056;                // 6144 f16  = 12288 B   (total 102400 B)

    hipLaunchKernelGGL(prep_weights, dim3(200), dim3(256), 0, stream, cw, fc1w, w1t, wct);

    const int B = in_sizes[0] / 3072;      // 16384
    hipLaunchKernelGGL(convnet_mfma, dim3(B / 16), dim3(256), 0, stream,
                       x, w1t, wct, fc1b, fc2w, fc2b, out);
}

// Round 5
// 50.625 us; speedup vs baseline: 2.9396x; 1.0530x over previous
//
#include <hip/hip_runtime.h>
#include <string.h>

// Fused ConvNet on MFMA: conv7x7 s3 (3->4) -> ^2 -> FC 324->64 -> ^2 -> FC 64->10
// conv + fc1 on v_mfma_f32_16x16x32_f16, fp16 hi/lo weight splitting.
// Block = 256 thr (4 waves) = 16 samples; sample pairs double-buffered in LDS.
// Round 5: conv A-build uses dword-floor ds_read_b32 x4 (hi2 folded into the
// address) + alignbit only; all per-tile geometry hoisted out of the pair loop.

typedef _Float16 f16;
typedef f16 f16x8 __attribute__((ext_vector_type(8)));
typedef __fp16 fp16x2 __attribute__((ext_vector_type(2)));
typedef float f32x4 __attribute__((ext_vector_type(4)));
typedef unsigned long long ull;

#define YSQ_B   27648                  // byte offset of YSQ region
#define LDS_B   (27648 + 11520)        // XS[2][2][3456]h + YSQ[16][360]h
#define BUFB    13824                  // byte stride of XS double-buffer

__device__ __forceinline__ unsigned pack_rtz(float a, float b) {
    fp16x2 h = __builtin_amdgcn_cvt_pkrtz(a, b);
    unsigned u; memcpy(&u, &h, 4); return u;
}

__device__ __forceinline__ void stage_pair(f16* XSH, int buf, const float4 ld[6], int t) {
#pragma unroll
    for (int i = 0; i < 6; ++i) {
        int idx = i * 256 + t;                 // 0..1535 (2 samples x 768 float4)
        int sp  = idx >= 768;
        int within = idx - sp * 768;
        int ci  = within >> 8;
        int rem = within & 255;
        int row = rem >> 3;
        int q   = rem & 7;
        int h0  = buf * 6912 + sp * 3456 + ci * 1152 + row * 36 + q * 4;
        float4 v = ld[i];
        unsigned u0 = pack_rtz(v.x, v.y), u1 = pack_rtz(v.z, v.w);
        *(ull*)(XSH + h0) = ((ull)u1 << 32) | u0;
    }
}

// ---------------- weight prep: fp16 hi/lo transposed layouts in ws ----------------
__global__ void prep_weights(const float* __restrict__ cw, const float* __restrict__ fc1w,
                             f16* __restrict__ w1t, f16* __restrict__ wct) {
    int idx = blockIdx.x * 256 + threadIdx.x;
    if (idx < 45056) {
        int part = idx / 22528;
        int rem  = idx % 22528;
        int n = rem / 352, k = rem % 352;
        float v = (k < 324) ? fc1w[n * 324 + k] : 0.f;
        f16 hi = (f16)v;
        w1t[idx] = (part == 0) ? hi : (f16)(v - (float)hi);
    } else if (idx < 45056 + 6144) {
        int j = idx - 45056;
        int part = j / 3072;
        int rem  = j % 3072;
        int oc = rem / 192, k = rem % 192;
        int seg = k >> 3, kw = k & 7;
        float v = 0.f;
        if (oc < 4 && seg < 21 && kw < 7) {
            int ci = seg / 7, kh = seg % 7;
            v = cw[((oc * 3 + ci) * 7 + kh) * 7 + kw];
        }
        f16 hi = (f16)v;
        wct[j] = (part == 0) ? hi : (f16)(v - (float)hi);
    }
}

__global__ __launch_bounds__(256, 4) void convnet_mfma(
    const float* __restrict__ x,
    const f16*  __restrict__ w1t,     // [2][64][352]
    const f16*  __restrict__ wct,     // [2][16][192]
    const float* __restrict__ fc1b,
    const float* __restrict__ fc2w,
    const float* __restrict__ fc2b,
    float* __restrict__ out)
{
    __shared__ unsigned char lds[LDS_B];
    f16* XSH = (f16*)lds;                                   // [2][2][3456] halves
    f16* YS = (f16*)(lds + YSQ_B);                          // [16][360] halves
    float* HSQ = (float*)lds;                               // overlay on XS (post-conv)

    const int t    = threadIdx.x;
    const int lane = t & 63;
    const int w    = t >> 6;
    const int g    = lane >> 4;        // k-group / row-quad
    const int lr   = lane & 15;        // A-row-in-tile / B-col
    const size_t base_s = (size_t)blockIdx.x * 16;

    // hoist conv W fragments: [part][step]; lane holds col=lr, k=st*32+g*8..+7
    f16x8 wc[2][6];
#pragma unroll
    for (int part = 0; part < 2; ++part)
#pragma unroll
        for (int st = 0; st < 6; ++st)
            wc[part][st] = *(const f16x8*)(wct + part * 3072 + lr * 192 + st * 32 + g * 8);

    // ---- hoisted per-lane conv geometry ----
    // seg byte offsets for this lane's g (seg = st*4+g, clamped to 20)
    int segoff[6];
#pragma unroll
    for (int st = 0; st < 6; ++st) {
        int seg  = st * 4 + g;
        int segc = seg > 20 ? 20 : seg;
        int ci   = segc >= 14 ? 2 : (segc >= 7 ? 1 : 0);
        int kh   = segc - ci * 7;
        segoff[st] = 2304 * ci + 72 * kh;       // 8*(ci*288 + 9*kh)
    }
    // per-tile A base (bytes, hi2 folded in) + alignbit shift; tiles {w, w+4, w+8}
    const int ntiles = (w == 3) ? 2 : 3;
    int bA[3], shv[3], coff[3][4];
#pragma unroll
    for (int ti = 0; ti < 3; ++ti) {
        int tile = w + ti * 4;
        int grow = tile * 16 + lr;
        int growc = grow > 161 ? 161 : grow;
        int sp  = growc >= 81;
        int p   = growc - (sp ? 81 : 0);
        int oh  = (p * 57) >> 9;
        int ow  = p - oh * 9;
        int c3  = 3 * ow;
        int resid = c3 & 3;
        bA[ti]  = sp * 6912 + 216 * oh + 8 * (c3 >> 2) + ((resid >= 2) ? 4 : 0);
        shv[ti] = (resid & 1) << 4;
        // C-write halfword offsets (lr<4 lanes only), -1 = invalid row
#pragma unroll
        for (int r = 0; r < 4; ++r) {
            int gr = tile * 16 + g * 4 + r;
            if (ti < ntiles && gr < 162) {
                int sp2 = gr >= 81;
                int p2  = gr - (sp2 ? 81 : 0);
                coff[ti][r] = sp2 * 360 + lr * 81 + p2;
            } else coff[ti][r] = -1;
        }
    }

    // issue pair-0 loads
    float4 ld[6];
    {
        const float4* xg = (const float4*)(x + base_s * 3072);
#pragma unroll
        for (int i = 0; i < 6; ++i) ld[i] = xg[i * 256 + t];
    }
    // zero YSQ pad region (kills stale garbage)
#pragma unroll
    for (int i = 0; i < 3; ++i) {
        int idx = i * 256 + t;
        if (idx < 720) *(f32x4*)(lds + YSQ_B + idx * 16) = f32x4{0.f, 0.f, 0.f, 0.f};
    }
    stage_pair(XSH, 0, ld, t);
    __syncthreads();

    int bufB = 0;
    for (int pair = 0; pair < 8; ++pair) {
        if (pair < 7) {
            const float4* xg = (const float4*)(x + (base_s + (size_t)(pair + 1) * 2) * 3072);
#pragma unroll
            for (int i = 0; i < 6; ++i) ld[i] = xg[i * 256 + t];
        }
        f16* ysp = YS + pair * 720;            // this pair's YS base (2 samples)
#pragma unroll
        for (int ti = 0; ti < 3; ++ti) {
            if (ti < ntiles) {
                const unsigned char* pA = lds + (bufB + bA[ti]);
                const int sh = shv[ti];
                f32x4 acc = {0.f, 0.f, 0.f, 0.f};
#pragma unroll
                for (int st = 0; st < 6; ++st) {
                    const unsigned* q = (const unsigned*)(pA + segoff[st]);
                    unsigned r0 = q[0], r1 = q[1], r2 = q[2], r3 = q[3];
                    union { unsigned u[4]; f16x8 h; } af;
                    af.u[0] = __builtin_amdgcn_alignbit(r1, r0, sh);
                    af.u[1] = __builtin_amdgcn_alignbit(r2, r1, sh);
                    af.u[2] = __builtin_amdgcn_alignbit(r3, r2, sh);
                    af.u[3] = __builtin_amdgcn_alignbit(r3, r3, sh);   // 8th tap: pad (w=0)
                    acc = __builtin_amdgcn_mfma_f32_16x16x32_f16(af.h, wc[0][st], acc, 0, 0, 0);
                    acc = __builtin_amdgcn_mfma_f32_16x16x32_f16(af.h, wc[1][st], acc, 0, 0, 0);
                }
                if (lr < 4) {
#pragma unroll
                    for (int r = 0; r < 4; ++r) {
                        int off = coff[ti][r];
                        if (off >= 0) {
                            float y = acc[r];
                            ysp[off] = (f16)(y * y);
                        }
                    }
                }
            }
        }
        if (pair < 7) stage_pair(XSH, bufB ? 0 : 1, ld, t);
        __syncthreads();
        bufB ^= BUFB;
    }

    // ---------------- fc1: M=16 samples, N=64 (wave w -> ntile w), K=352 ----------------
    {
        f32x4 a1 = {0.f, 0.f, 0.f, 0.f};
        const int n = w * 16 + lr;
#pragma unroll
        for (int st = 0; st < 11; ++st) {
            f16x8 av = *(const f16x8*)(YS + lr * 360 + st * 32 + g * 8);
            f16x8 bh = *(const f16x8*)(w1t +          n * 352 + st * 32 + g * 8);
            f16x8 bl = *(const f16x8*)(w1t + 22528 +  n * 352 + st * 32 + g * 8);
            a1 = __builtin_amdgcn_mfma_f32_16x16x32_f16(av, bh, a1, 0, 0, 0);
            a1 = __builtin_amdgcn_mfma_f32_16x16x32_f16(av, bl, a1, 0, 0, 0);
        }
        float bias = fc1b[n];
#pragma unroll
        for (int r = 0; r < 4; ++r) {
            int s = g * 4 + r;                 // sample row
            float h = a1[r] + bias;
            HSQ[s * 65 + n] = h * h;
        }
    }
    __syncthreads();

    // ---------------- fc2: 160 outputs ----------------
    if (t < 160) {
        int sj = t / 10, j = t - sj * 10;
        float a = fc2b[j];
        const float* wr = fc2w + j * 64;
        const float* hv = &HSQ[sj * 65];
#pragma unroll
        for (int i = 0; i < 64; ++i) a += wr[i] * hv[i];
        out[(base_s + sj) * 10 + j] = a;
    }
}

extern "C" void kernel_launch(void* const* d_in, const int* in_sizes, int n_in,
                              void* d_out, int out_size, void* d_ws, size_t ws_size,
                              hipStream_t stream) {
    const float* x    = (const float*)d_in[0];
    const float* cw   = (const float*)d_in[1];
    const float* fc1w = (const float*)d_in[2];
    const float* fc1b = (const float*)d_in[3];
    const float* fc2w = (const float*)d_in[4];
    const float* fc2b = (const float*)d_in[5];
    float* out = (float*)d_out;

    f16* w1t = (f16*)d_ws;                 // 45056 f16 = 90112 B
    f16* wct = w1t + 45056;                // 6144 f16  = 12288 B

    hipLaunchKernelGGL(prep_weights, dim3(200), dim3(256), 0, stream, cw, fc1w, w1t, wct);

    const int B = in_sizes[0] / 3072;      // 16384
    hipLaunchKernelGGL(convnet_mfma, dim3(B / 16), dim3(256), 0, stream,
                       x, w1t, wct, fc1b, fc2w, fc2b, out);
}